// Round 5
// baseline (1346.882 us; speedup 1.0000x reference)
//
#include <hip/hip_runtime.h>
#include <math.h>

#define BS 4
#define CC 28          // total channels in obs / maps
#define NF 25          // 1 + NUM_SEM splat feature channels
#define HS 240
#define WSC 320
#define NPIX (HS*WSC)
#define VR 100
#define ZD 80
#define MC 480
#define NCELL (VR*VR)                  // 10000 xy cells per batch
#define NREC_MAX ((size_t)BS*NPIX*4)   // 1,228,800 worst-case records

__device__ __forceinline__ float clip01(float v){ return fminf(fmaxf(v, 0.f), 1.f); }

// ---------------- shared geometry (identical in prep/scatter) ----------------
struct Geo {
    float wx[2], wy[2], wz[2];
    int   xi[2], yi[2], zi[2];
    bool  sx[2], sy[2];
};

__device__ __forceinline__ Geo compute_geo(const float* __restrict__ obs,
                                           const float* __restrict__ view_angles,
                                           int b, int pix){
    int j = pix % WSC;
    int i = pix / WSC;
    float depth = obs[((size_t)(b*CC + 3))*NPIX + pix];
    if (depth < 0.f) depth = 10000.f;
    const float FOCAL = 277.12812921102035f;
    float X = ((float)j - 159.5f) * depth / FOCAL;
    float Z = ((float)(HS-1-i) - 119.5f) * depth / FOCAL;
    float a = view_angles[b] * 0.017453292519943295f;
    float ca = cosf(a), sa = sinf(a);
    float Y2 = ca*depth - sa*Z;
    float Z2 = sa*depth + ca*Z + 155.f;   // + AGENT_HEIGHT
    float X2 = X + 250.f;                 // + SHIFT_X

    // replicate reference arithmetic chain exactly
    float px = ((X2/5.f - 50.f)/100.f*2.f)*50.f + 50.f;
    float py = ((Y2/5.f - 50.f)/100.f*2.f)*50.f + 50.f;
    float pz = ((Z2/5.f - 32.f)/80.f*2.f)*40.f + 40.f;

    Geo g;
    float fx = floorf(px), fy = floorf(py), fz = floorf(pz);
    {
        float p0 = fx, p1 = fx + 1.f;
        g.sx[0] = (p0 > 0.f) && (p0 < 100.f);
        g.sx[1] = (p1 > 0.f) && (p1 < 100.f);
        g.wx[0] = g.sx[0] ? (1.f - fabsf(px - p0)) : 0.f;
        g.wx[1] = g.sx[1] ? (1.f - fabsf(px - p1)) : 0.f;
        g.xi[0] = g.sx[0] ? (int)p0 : 0;
        g.xi[1] = g.sx[1] ? (int)p1 : 0;
    }
    {
        float p0 = fy, p1 = fy + 1.f;
        g.sy[0] = (p0 > 0.f) && (p0 < 100.f);
        g.sy[1] = (p1 > 0.f) && (p1 < 100.f);
        g.wy[0] = g.sy[0] ? (1.f - fabsf(py - p0)) : 0.f;
        g.wy[1] = g.sy[1] ? (1.f - fabsf(py - p1)) : 0.f;
        g.yi[0] = g.sy[0] ? (int)p0 : 0;
        g.yi[1] = g.sy[1] ? (int)p1 : 0;
    }
    {
        float p0 = fz, p1 = fz + 1.f;
        bool s0 = (p0 > 0.f) && (p0 < 80.f);
        bool s1 = (p1 > 0.f) && (p1 < 80.f);
        g.wz[0] = s0 ? (1.f - fabsf(pz - p0)) : 0.f;
        g.wz[1] = s1 ? (1.f - fabsf(pz - p1)) : 0.f;
        g.zi[0] = s0 ? (int)p0 : 0;
        g.zi[1] = s1 ? (int)p1 : 0;
    }
    return g;
}

// ---------------- pass A: count records + transpose features ----------------
__global__ __launch_bounds__(256)
void prep_kernel(const float* __restrict__ obs,
                 const float* __restrict__ view_angles,
                 int* __restrict__ counts,
                 float* __restrict__ feat){
    __shared__ float sf[6400];          // 256 px * 24 f, padded stride 25
    int t   = threadIdx.x;
    int tid = blockIdx.x * 256 + t;
    int b   = tid / NPIX;
    int pix = tid % NPIX;

    Geo g = compute_geo(obs, view_angles, b, pix);
    #pragma unroll
    for (int cy = 0; cy < 2; ++cy)
    #pragma unroll
    for (int cx = 0; cx < 2; ++cx){
        if (g.sx[cx] && g.sy[cy] && (g.wx[cx]*g.wy[cy] != 0.f))
            atomicAdd(&counts[b*NCELL + g.yi[cy]*VR + g.xi[cx]], 1);
    }

    #pragma unroll 6
    for (int f = 0; f < 24; ++f)
        sf[t*25 + f] = obs[((size_t)(b*CC + 4 + f))*NPIX + pix];
    __syncthreads();
    size_t base = ((size_t)b*NPIX + (size_t)(pix - t)) * 24;
    for (int q = t; q < 6144; q += 256)
        feat[base + q] = sf[q + q/24];
}

// ---------------- pass B: coalesced wave-shuffle scan + pose fold-in ----------------
__global__ __launch_bounds__(1024)
void scan_pose_kernel(const int* __restrict__ counts,
                      int* __restrict__ bases,
                      int* __restrict__ cursor,
                      const float* __restrict__ pose_obs,
                      const float* __restrict__ poses_last,
                      float* __restrict__ out_p1,
                      float* __restrict__ out_p2,
                      float* __restrict__ params){
    __shared__ int wsum[16];
    __shared__ int carry_s;
    int t = threadIdx.x;
    int lane = t & 63, wid = t >> 6;
    if (t == 0) carry_s = 0;

    if (t >= 32 && t < 32 + BS){          // pose: 4 threads, away from t==0
        int b = t - 32;
        const float R2D = 57.29577951308232f;
        float th0 = poses_last[b*3+2] / R2D;
        float s0 = sinf(th0), c0 = cosf(th0);
        float ny = poses_last[b*3+1] + pose_obs[b*3+0]*s0 + pose_obs[b*3+1]*c0;
        float nx = poses_last[b*3+0] + pose_obs[b*3+0]*c0 - pose_obs[b*3+1]*s0;
        float no = poses_last[b*3+2] + pose_obs[b*3+2]*R2D;
        no = fmodf(no - 180.f, 360.f) + 180.f;
        no = fmodf(no + 180.f, 360.f) - 180.f;
        out_p1[b*3+0] = nx; out_p1[b*3+1] = ny; out_p1[b*3+2] = no;
        out_p2[b*3+0] = nx; out_p2[b*3+1] = ny; out_p2[b*3+2] = no;
        const float half = 240.f;
        float sxp = -(nx*100.f/5.f - half)/half;
        float syp = -(ny*100.f/5.f - half)/half;
        float tt = (90.f - no) * 0.017453292519943295f;
        params[b*4+0] = cosf(tt);
        params[b*4+1] = sinf(tt);
        params[b*4+2] = sxp;
        params[b*4+3] = syp;
    }
    __syncthreads();

    const int TOT = BS*NCELL;           // 40000
    for (int tile = 0; tile < 40; ++tile){
        int idx = tile*1024 + t;
        int v = (idx < TOT) ? counts[idx] : 0;
        int s = v;
        #pragma unroll
        for (int off = 1; off < 64; off <<= 1){
            int u = __shfl_up(s, off, 64);
            if (lane >= off) s += u;
        }
        if (lane == 63) wsum[wid] = s;
        __syncthreads();
        if (t < 16){
            int ws = wsum[t];
            #pragma unroll
            for (int off = 1; off < 16; off <<= 1){
                int u = __shfl_up(ws, off, 64);
                if (t >= off) ws += u;
            }
            wsum[t] = ws;
        }
        __syncthreads();
        int excl    = carry_s + (wid ? wsum[wid-1] : 0) + s - v;
        int tiletot = wsum[15];
        if (idx < TOT){ bases[idx] = excl; cursor[idx] = excl; }
        __syncthreads();
        if (t == 0) carry_s += tiletot;
        __syncthreads();
    }
}

// ---------------- pass C: scatter self-contained records ----------------
__global__ __launch_bounds__(256)
void scatter_kernel(const float* __restrict__ obs,
                    const float* __restrict__ view_angles,
                    int* __restrict__ cursor,
                    uint4* __restrict__ records){
    int tid = blockIdx.x * 256 + threadIdx.x;
    int b   = tid / NPIX;
    int pix = tid % NPIX;
    Geo g = compute_geo(obs, view_angles, b, pix);
    #pragma unroll
    for (int cy = 0; cy < 2; ++cy)
    #pragma unroll
    for (int cx = 0; cx < 2; ++cx){
        float wxy = g.wx[cx] * g.wy[cy];
        if (g.sx[cx] && g.sy[cy] && (wxy != 0.f)){
            int cid = b*NCELL + g.yi[cy]*VR + g.xi[cx];
            int pos = atomicAdd(&cursor[cid], 1);
            float w0 = wxy * g.wz[0];        // matches ref (wx*wy)*wz order
            float w1 = wxy * g.wz[1];
            unsigned iw = (unsigned)pix | ((unsigned)g.zi[0] << 17)
                                        | ((unsigned)g.zi[1] << 24);
            records[pos] = make_uint4(__float_as_uint(w0), __float_as_uint(w1), iw, 0u);
        }
    }
}

// ---------------- pass D: per-cell LDS accumulation + z-projection ----------------
__global__ __launch_bounds__(256)
void accum_kernel(const uint4* __restrict__ records,
                  const float* __restrict__ feat,
                  const int* __restrict__ bases,
                  const int* __restrict__ counts,
                  float* __restrict__ ahp,
                  float* __restrict__ allp,
                  float* __restrict__ out0){
    __shared__ float col[ZD*NF];        // 2000 floats
    __shared__ float pall[200], pag[200];
    __shared__ uint4 rbuf[250];

    int cid = blockIdx.x;
    int b   = cid / NCELL;
    int rest = cid % NCELL;
    int y = rest / VR;
    int x = rest % VR;
    int t = threadIdx.x;
    int n = counts[cid];

    if (n == 0){        // uniform early-exit: write zeros, skip everything
        if (t < NF) ahp[(((size_t)b*NF + t)*VR + y)*VR + x] = 0.f;
        if (t == 0){
            allp[((size_t)b*VR + y)*VR + x] = 0.f;
            out0[(size_t)b*NCELL + y*VR + x] = 0.f;
        }
        return;
    }

    for (int i = t; i < ZD*NF; i += 256) col[i] = 0.f;

    int start = bases[cid];
    int r = t / NF;                     // record slot within chunk (0..9)
    int f = t % NF;
    bool act = t < 250;
    const float* feat_b = feat + (size_t)b*NPIX*24;

    for (int tile = 0; tile < n; tile += 250){
        int m = min(250, n - tile);
        if (t < m) rbuf[t] = records[start + tile + t];   // coalesced stage
        __syncthreads();                                  // also covers col zero-init

        // software-pipelined: feat load issued one chunk ahead
        int idx = r;
        bool v = act && (idx < m);
        uint4 rec = v ? rbuf[idx] : make_uint4(0u,0u,0u,0u);
        float val = 1.f;
        if (v && f) val = feat_b[(size_t)(rec.z & 0x1FFFFu)*24 + (f-1)];

        for (int cb = 0; cb < m; cb += 10){
            int idx2 = cb + 10 + r;
            bool v2 = act && (idx2 < m);
            uint4 rec2 = v2 ? rbuf[idx2] : make_uint4(0u,0u,0u,0u);
            float val2 = 1.f;
            if (v2 && f) val2 = feat_b[(size_t)(rec2.z & 0x1FFFFu)*24 + (f-1)];

            if (v){
                float w0 = __uint_as_float(rec.x);
                float w1 = __uint_as_float(rec.y);
                int z0 = (int)((rec.z >> 17) & 0x7Fu);
                int z1 = (int)((rec.z >> 24) & 0x7Fu);
                if (w0 != 0.f) atomicAdd(&col[z0*NF + f], val * w0);
                if (w1 != 0.f) atomicAdd(&col[z1*NF + f], val * w1);
            }
            rec = rec2; val = val2; v = v2;
        }
        __syncthreads();
    }

    // projection: 200 threads = 25 f x 8 z-groups of 10
    if (t < 200){
        int ff = t % NF;
        int gq = t / NF;
        float sall = 0.f, sag = 0.f;
        for (int z = gq*10; z < gq*10 + 10; ++z){
            float rv = rintf(col[z*NF + ff]);
            sall += rv;
            if (z >= 11 && z < 49) sag += rv;   // agent-height z range
        }
        pall[t] = sall;
        pag[t]  = sag;
    }
    __syncthreads();
    if (t < NF){
        float a = 0.f, s = 0.f;
        #pragma unroll
        for (int gq = 0; gq < 8; ++gq){
            s += pall[gq*NF + t];
            a += pag[gq*NF + t];
        }
        ahp[(((size_t)b*NF + t)*VR + y)*VR + x] = a;
        if (t == 0){
            allp[((size_t)b*VR + y)*VR + x] = s;
            out0[(size_t)b*NCELL + y*VR + x] = clip01(a);   // fp_map_pred
        }
    }
}

// ---------------- exact per-pixel double-bilinear (slow path) ----------------
__device__ void final_pixel(const float* __restrict__ ahp_b,
                            const float* __restrict__ allp_b,
                            const float* __restrict__ maps_last,
                            float* __restrict__ out1,
                            float ct, float st, float sx, float sy,
                            int b, int h, int w){
    float gx = -1.f + 2.f*(float)w/479.f;
    float gy = -1.f + 2.f*(float)h/479.f;
    float ix = (gx + sx + 1.f)*0.5f*479.f;
    float iy = (gy + sy + 1.f)*0.5f*479.f;
    float x0 = floorf(ix), y0 = floorf(iy);
    float wx1 = ix - x0, wx0 = 1.f - wx1;
    float wy1 = iy - y0, wy0 = 1.f - wy1;

    int   offs[16];
    float wt16[16];
    int nz = 0;
    #pragma unroll
    for (int tc = 0; tc < 4; ++tc){
        float txf = (tc & 1) ? x0 + 1.f : x0;
        float tyf = (tc & 2) ? y0 + 1.f : y0;
        float wt  = ((tc & 1) ? wx1 : wx0) * ((tc & 2) ? wy1 : wy0);
        bool validT = (txf >= 0.f) && (txf <= 479.f) && (tyf >= 0.f) && (tyf <= 479.f);
        int txc = (int)fminf(fmaxf(txf, 0.f), 479.f);
        int tyc = (int)fminf(fmaxf(tyf, 0.f), 479.f);

        float gx2 = -1.f + 2.f*(float)txc/479.f;
        float gy2 = -1.f + 2.f*(float)tyc/479.f;
        float rgx = ct*gx2 - st*gy2;
        float rgy = st*gx2 + ct*gy2;
        float ixr = (rgx + 1.f)*0.5f*479.f;
        float iyr = (rgy + 1.f)*0.5f*479.f;
        float rx0 = floorf(ixr), ry0 = floorf(iyr);
        float rwx1 = ixr - rx0, rwx0 = 1.f - rwx1;
        float rwy1 = iyr - ry0, rwy0 = 1.f - rwy1;

        #pragma unroll
        for (int rc = 0; rc < 4; ++rc){
            int id = tc*4 + rc;
            float rxf = (rc & 1) ? rx0 + 1.f : rx0;
            float ryf = (rc & 2) ? ry0 + 1.f : ry0;
            float wr  = ((rc & 1) ? rwx1 : rwx0) * ((rc & 2) ? rwy1 : rwy0);
            bool validR = (rxf >= 0.f) && (rxf <= 479.f) && (ryf >= 0.f) && (ryf <= 479.f);
            int rxc = (int)fminf(fmaxf(rxf, 0.f), 479.f);
            int ryc = (int)fminf(fmaxf(ryf, 0.f), 479.f);
            bool inwin = validT && validR &&
                         (rxc >= 190) && (rxc < 290) && (ryc >= 240) && (ryc < 336);
            float wgt = wt * wr;
            if (inwin && wgt != 0.f){
                offs[id] = (ryc - 240)*VR + (rxc - 190);
                wt16[id] = wgt;
                nz++;
            } else {
                offs[id] = -1;
                wt16[id] = 0.f;
            }
        }
    }

    size_t outBase = (size_t)b*CC*MC*MC + (size_t)h*MC + w;
    if (nz == 0){
        #pragma unroll
        for (int ch = 0; ch < CC; ++ch){
            size_t o = outBase + (size_t)ch*MC*MC;
            out1[o] = fmaxf(maps_last[o], 0.f);
        }
        return;
    }
    for (int ch = 0; ch < CC; ++ch){
        float acc = 0.f;
        if (ch != 2 && ch != 3){
            #pragma unroll
            for (int id = 0; id < 16; ++id){
                if (offs[id] >= 0){
                    float v;
                    if (ch == 0)      v = clip01(ahp_b[offs[id]]);
                    else if (ch == 1) v = clip01(allp_b[offs[id]]);
                    else              v = clip01(ahp_b[(size_t)(ch-3)*VR*VR + offs[id]] / 5.f);
                    acc += wt16[id] * v;
                }
            }
        }
        size_t o = outBase + (size_t)ch*MC*MC;
        out1[o] = fmaxf(maps_last[o], acc);
    }
}

// ---------------- fused rotate+translate grid_sample + max, 4-wide ----------------
__global__ __launch_bounds__(256)
void final_kernel(const float* __restrict__ ahp,
                  const float* __restrict__ allp,
                  const float* __restrict__ params,
                  const float* __restrict__ maps_last,
                  float* __restrict__ out1){
    int tid = blockIdx.x * blockDim.x + threadIdx.x;
    const int WQ = MC/4;                 // 120
    if (tid >= BS*MC*WQ) return;
    int w4 = (tid % WQ) * 4;
    int h  = (tid / WQ) % MC;
    int b  = tid / (WQ*MC);

    float ct = params[b*4+0], st = params[b*4+1];
    float sx = params[b*4+2], sy = params[b*4+3];
    float gy = -1.f + 2.f*(float)h/479.f;

    // conservative composed-affine window test (margin 4 px covers both
    // bilinear integer-roundings: |txc-ix|<=1 -> <=~1.42 px after rotation,
    // plus rotate-corner +1 px)
    bool anywin = false;
    #pragma unroll
    for (int k = 0; k < 4; ++k){
        float gx = -1.f + 2.f*(float)(w4+k)/479.f;
        float cgx = ct*(gx+sx) - st*(gy+sy);
        float cgy = st*(gx+sx) + ct*(gy+sy);
        float exu = (cgx + 1.f)*0.5f*479.f;
        float exv = (cgy + 1.f)*0.5f*479.f;
        anywin |= (exu > 186.f) && (exu < 293.f) && (exv > 236.f) && (exv < 339.f);
    }

    size_t pbase = (size_t)b*CC*MC*MC + (size_t)h*MC + w4;
    if (!anywin){
        #pragma unroll 4
        for (int ch = 0; ch < CC; ++ch){
            const float4 mv = *(const float4*)(maps_last + pbase + (size_t)ch*MC*MC);
            float4 o;
            o.x = fmaxf(mv.x, 0.f); o.y = fmaxf(mv.y, 0.f);
            o.z = fmaxf(mv.z, 0.f); o.w = fmaxf(mv.w, 0.f);
            *(float4*)(out1 + pbase + (size_t)ch*MC*MC) = o;
        }
        return;
    }

    const float* ahp_b  = ahp  + (size_t)b*NF*VR*VR;
    const float* allp_b = allp + (size_t)b*VR*VR;
    for (int k = 0; k < 4; ++k)
        final_pixel(ahp_b, allp_b, maps_last, out1, ct, st, sx, sy, b, h, w4+k);
}

extern "C" void kernel_launch(void* const* d_in, const int* in_sizes, int n_in,
                              void* d_out, int out_size, void* d_ws, size_t ws_size,
                              hipStream_t stream){
    const float* obs         = (const float*)d_in[0];
    const float* pose_obs    = (const float*)d_in[1];
    const float* maps_last   = (const float*)d_in[2];
    const float* poses_last  = (const float*)d_in[3];
    const float* view_angles = (const float*)d_in[4];
    float* out = (float*)d_out;

    const size_t OUT0 = (size_t)BS*VR*VR;        // 40000
    const size_t OUT1 = (size_t)BS*CC*MC*MC;     // 25,804,800
    float* out0 = out;
    float* out1 = out + OUT0;
    float* out2 = out + OUT0 + OUT1;
    float* out3 = out2 + BS*3;

    const size_t AHP_FLOATS  = (size_t)BS*NF*VR*VR;   // 1,000,000
    const size_t ALLP_FLOATS = (size_t)BS*VR*VR;      // 40,000
    const size_t NCID        = (size_t)BS*NCELL;      // 40,000
    const size_t FEAT_FLOATS = (size_t)BS*NPIX*24;    // 7,372,800 (29.5 MB)

    // small arrays read by final_kernel — always in ws
    float* ahp    = (float*)d_ws;
    float* allp   = ahp  + AHP_FLOATS;
    float* params = allp + ALLP_FLOATS;
    char*  ws_tail = (char*)(params + 16);
    size_t ws_used_small = (size_t)(ws_tail - (char*)d_ws);

    // big transient arrays: counts/bases/cursor + records + feat
    const size_t BIG_BYTES = NCID*3*4 + 32 + NREC_MAX*16 + FEAT_FLOATS*4;  // ~49.7 MB
    char* big;
    if (ws_size >= ws_used_small + BIG_BYTES){
        big = ws_tail;
    } else {
        big = (char*)(out1 + OUT1) - BIG_BYTES;   // consumed before final_kernel writes
        big = (char*)((uintptr_t)big & ~(uintptr_t)15);
    }
    int* counts = (int*)big;
    int* bases  = counts + NCID;
    int* cursor = bases  + NCID;
    uint4* records = (uint4*)(((uintptr_t)(cursor + NCID) + 15) & ~(uintptr_t)15);
    float* feat    = (float*)(records + NREC_MAX);

    hipMemsetAsync(counts, 0, NCID*4, stream);

    int nblk = (BS*NPIX)/256;   // 1200, exact
    prep_kernel<<<nblk, 256, 0, stream>>>(obs, view_angles, counts, feat);
    scan_pose_kernel<<<1, 1024, 0, stream>>>(counts, bases, cursor,
                                             pose_obs, poses_last, out2, out3, params);
    scatter_kernel<<<nblk, 256, 0, stream>>>(obs, view_angles, cursor, records);
    accum_kernel<<<(int)NCID, 256, 0, stream>>>(records, feat, bases, counts,
                                                ahp, allp, out0);
    final_kernel<<<(BS*MC*(MC/4) + 255)/256, 256, 0, stream>>>(ahp, allp, params,
                                                               maps_last, out1);
}